// Round 1
// baseline (587.825 us; speedup 1.0000x reference)
//
#include <hip/hip_runtime.h>

typedef _Float16 half8 __attribute__((ext_vector_type(8)));
typedef float floatx4 __attribute__((ext_vector_type(4)));

__device__ __forceinline__ float sigmoidf_(float x) {
    return 1.0f / (1.0f + __expf(-x));
}
__device__ __forceinline__ float tanhf_(float x) {
    x = fminf(fmaxf(x, -20.0f), 20.0f);
    float e = __expf(2.0f * x);
    return (e - 1.0f) / (e + 1.0f);
}

// One bidirectional LSTM layer. Grid = 256 blocks: blockIdx 0..127 forward
// (8 batch rows each), 128..255 backward. Block = 256 threads (4 waves).
// Per step: z[8, 4U] = [x_t ; h] @ [Wk ; Wr] + b  via mfma_f32_16x16x32_f16
// (M=16, rows 8..15 dead), gates in fp32, c persistent in VGPRs.
template<int F, int U, int KT, int NT, bool IN_F32, bool SEQ_OUT>
__global__ __launch_bounds__(256)
void lstm_layer(const void* __restrict__ in_,
                const float* __restrict__ Wk_f, const float* __restrict__ Wr_f,
                const float* __restrict__ b_f,
                const float* __restrict__ Wk_b, const float* __restrict__ Wr_b,
                const float* __restrict__ b_b,
                _Float16* __restrict__ hseq, float* __restrict__ hlast)
{
    constexpr int T  = 128;
    constexpr int N  = NT * 16;       // == 4U
    constexpr int K  = F + U;
    constexpr int KP = KT * 32;       // padded K
    constexpr int MC = 8;             // chains per block
    constexpr int NTW = NT / 4;       // n-tiles per wave
    constexpr int TOT = MC * F;       // staged input elems per step
    constexpr int PFE = (TOT + 255) / 256;
    constexpr int SETS = (MC * U + 255) / 256;

    const int tid  = threadIdx.x;
    const int wave = tid >> 6;
    const int lane = tid & 63;
    const int quad = lane >> 4;
    const int l16  = lane & 15;

    const int dir   = blockIdx.x >> 7;          // 0 fwd, 1 bwd
    const int bbase = (blockIdx.x & 127) * MC;  // batch rows of this block

    const float* Wk = dir ? Wk_b : Wk_f;
    const float* Wr = dir ? Wr_b : Wr_f;
    const float* bs = dir ? b_b  : b_f;

    __shared__ __align__(16) _Float16 A[16][KP];  // [chain][k] f16 operand tile
    __shared__ float Z[MC][N];                    // pre-activation gates

    // zero the whole A tile once: covers h0=0, K padding, dead rows 8..15
    for (int i = tid; i < 16 * KP; i += 256)
        (&A[0][0])[i] = (_Float16)0.0f;

    // Build B fragments (weights, f16) in registers.
    // B-frag layout for 16x16x32: lane holds B[k = quad*8+j][n = lane&15].
    half8 bf[NTW][KT];
    #pragma unroll
    for (int nt = 0; nt < NTW; nt++) {
        const int n = (wave * NTW + nt) * 16 + l16;
        #pragma unroll
        for (int kt = 0; kt < KT; kt++) {
            half8 h;
            #pragma unroll
            for (int j = 0; j < 8; j++) {
                const int k = kt * 32 + quad * 8 + j;
                float v = 0.0f;
                if (k < F)      v = Wk[k * N + n];
                else if (k < K) v = Wr[(k - F) * N + n];
                h[j] = (_Float16)v;
            }
            bf[nt][kt] = h;
        }
    }
    float bias_r[NTW];
    #pragma unroll
    for (int nt = 0; nt < NTW; nt++)
        bias_r[nt] = bs[(wave * NTW + nt) * 16 + l16];

    float c_reg[SETS];
    #pragma unroll
    for (int s = 0; s < SETS; s++) c_reg[s] = 0.0f;

    // prefetch x_0
    float xr[PFE];
    {
        const int t_in = dir ? (T - 1) : 0;
        #pragma unroll
        for (int i = 0; i < PFE; i++) {
            const int e = tid + i * 256;
            if (e < TOT) {
                const int m = e / F, k = e - m * F;
                const long idx = ((long)(bbase + m) * T + t_in) * F + k;
                xr[i] = IN_F32 ? ((const float*)in_)[idx]
                               : (float)((const _Float16*)in_)[idx];
            }
        }
    }
    __syncthreads();   // A zero-init visible before first x-stage overlap

    for (int t = 0; t < T; t++) {
        // stage x_t into A[:, 0:F)
        #pragma unroll
        for (int i = 0; i < PFE; i++) {
            const int e = tid + i * 256;
            if (e < TOT) {
                const int m = e / F, k = e - m * F;
                A[m][k] = (_Float16)xr[i];
            }
        }
        __syncthreads();   // barrier 1: A (x + h) complete before MFMA reads

        // prefetch x_{t+1} (latency hidden behind MFMA + gates)
        if (t + 1 < T) {
            const int t_in = dir ? (T - 2 - t) : (t + 1);
            #pragma unroll
            for (int i = 0; i < PFE; i++) {
                const int e = tid + i * 256;
                if (e < TOT) {
                    const int m = e / F, k = e - m * F;
                    const long idx = ((long)(bbase + m) * T + t_in) * F + k;
                    xr[i] = IN_F32 ? ((const float*)in_)[idx]
                                   : (float)((const _Float16*)in_)[idx];
                }
            }
        }

        // z = [x;h] @ [Wk;Wr] + b
        floatx4 acc[NTW];
        #pragma unroll
        for (int nt = 0; nt < NTW; nt++) {
            floatx4 v = {bias_r[nt], bias_r[nt], bias_r[nt], bias_r[nt]};
            acc[nt] = v;
        }
        #pragma unroll
        for (int kt = 0; kt < KT; kt++) {
            const half8 a = *(const half8*)&A[l16][kt * 32 + quad * 8];
            #pragma unroll
            for (int nt = 0; nt < NTW; nt++)
                acc[nt] = __builtin_amdgcn_mfma_f32_16x16x32_f16(a, bf[nt][kt], acc[nt], 0, 0, 0);
        }
        // scatter z to LDS (C/D layout: row=(quad*4+r), col=lane&15)
        #pragma unroll
        for (int nt = 0; nt < NTW; nt++) {
            const int col = (wave * NTW + nt) * 16 + l16;
            #pragma unroll
            for (int r = 0; r < 4; r++) {
                const int row = quad * 4 + r;
                if (row < MC) Z[row][col] = acc[nt][r];
            }
        }
        __syncthreads();   // barrier 2: Z complete, all A-reads retired

        // gates: thread handles (chain m, unit u) sets
        #pragma unroll
        for (int s = 0; s < SETS; s++) {
            const int sid = tid + s * 256;
            if (sid < MC * U) {
                const int m = sid / U, u = sid - m * U;
                const float zi = Z[m][u];
                const float zf = Z[m][U + u];
                const float zg = Z[m][2 * U + u];
                const float zo = Z[m][3 * U + u];
                const float ig = sigmoidf_(zi);
                const float fg = sigmoidf_(zf);
                const float gg = tanhf_(zg);
                const float og = sigmoidf_(zo);
                const float c  = fg * c_reg[s] + ig * gg;
                c_reg[s] = c;
                const float h  = og * tanhf_(c);
                A[m][F + u] = (_Float16)h;   // h-region for next step's MFMA
                if constexpr (SEQ_OUT) {
                    // backward dir re-reversed (Keras concat semantics)
                    const int tp = dir ? (T - 1 - t) : t;
                    hseq[((long)(bbase + m) * T + tp) * (2 * U) + dir * U + u] = (_Float16)h;
                } else {
                    if (t == T - 1)
                        hlast[(bbase + m) * (2 * U) + dir * U + u] = h;
                }
            }
        }
        // no barrier needed: next x-stage writes A[:,0:F) — disjoint from
        // h-region writes and Z reads; MFMA reads only after barrier 1.
    }
}

__global__ __launch_bounds__(256)
void dense_head(const float* __restrict__ h3,
                const float* __restrict__ w1, const float* __restrict__ b1,
                const float* __restrict__ w2, const float* __restrict__ b2,
                float* __restrict__ out)
{
    const int r = blockIdx.x * 256 + threadIdx.x;
    if (r >= 1024) return;
    float h[32];
    #pragma unroll
    for (int k = 0; k < 32; k++) h[k] = h3[r * 32 + k];
    float d1[8];
    #pragma unroll
    for (int j = 0; j < 8; j++) {
        float a = b1[j];
        #pragma unroll
        for (int k = 0; k < 32; k++) a += h[k] * w1[k * 8 + j];
        d1[j] = fmaxf(a, 0.0f);
    }
    #pragma unroll
    for (int c = 0; c < 3; c++) {
        float s = b2[c];
        #pragma unroll
        for (int j = 0; j < 8; j++) s += d1[j] * w2[j * 3 + c];
        out[r * 3 + c] = 1.0f / (1.0f + __expf(-s));
    }
}

extern "C" void kernel_launch(void* const* d_in, const int* in_sizes, int n_in,
                              void* d_out, int out_size, void* d_ws, size_t ws_size,
                              hipStream_t stream) {
    const float* x     = (const float*)d_in[0];
    const float* w1f_k = (const float*)d_in[1];
    const float* w1f_r = (const float*)d_in[2];
    const float* w1f_b = (const float*)d_in[3];
    const float* w1b_k = (const float*)d_in[4];
    const float* w1b_r = (const float*)d_in[5];
    const float* w1b_b = (const float*)d_in[6];
    const float* w2f_k = (const float*)d_in[7];
    const float* w2f_r = (const float*)d_in[8];
    const float* w2f_b = (const float*)d_in[9];
    const float* w2b_k = (const float*)d_in[10];
    const float* w2b_r = (const float*)d_in[11];
    const float* w2b_b = (const float*)d_in[12];
    const float* w3f_k = (const float*)d_in[13];
    const float* w3f_r = (const float*)d_in[14];
    const float* w3f_b = (const float*)d_in[15];
    const float* w3b_k = (const float*)d_in[16];
    const float* w3b_r = (const float*)d_in[17];
    const float* w3b_b = (const float*)d_in[18];
    const float* d3_w  = (const float*)d_in[19];
    const float* d3_b  = (const float*)d_in[20];
    const float* cls_w = (const float*)d_in[21];
    const float* cls_b = (const float*)d_in[22];

    char* ws = (char*)d_ws;
    _Float16* h1 = (_Float16*)ws;                               // [1024][128][128] f16 = 32MB
    _Float16* h2 = (_Float16*)(ws + (size_t)33554432);          // [1024][128][64]  f16 = 16MB
    float*    h3 = (float*)(ws + (size_t)33554432 + 16777216);  // [1024][32]       f32

    dim3 grid(256), blk(256);
    // L1: F=78, U=64, K=142 -> 5 K-tiles, N=256 -> 16 n-tiles
    lstm_layer<78, 64, 5, 16, true, true><<<grid, blk, 0, stream>>>(
        x, w1f_k, w1f_r, w1f_b, w1b_k, w1b_r, w1b_b, h1, nullptr);
    // L2: F=128, U=32, K=160 -> 5 K-tiles, N=128 -> 8 n-tiles
    lstm_layer<128, 32, 5, 8, false, true><<<grid, blk, 0, stream>>>(
        h1, w2f_k, w2f_r, w2f_b, w2b_k, w2b_r, w2b_b, h2, nullptr);
    // L3: F=64, U=16, K=80 -> 3 K-tiles, N=64 -> 4 n-tiles, last-state only
    lstm_layer<64, 16, 3, 4, false, false><<<grid, blk, 0, stream>>>(
        h2, w3f_k, w3f_r, w3f_b, w3b_k, w3b_r, w3b_b, nullptr, h3);

    dense_head<<<dim3(4), blk, 0, stream>>>(h3, d3_w, d3_b, cls_w, cls_b, (float*)d_out);
}

// Round 2
// 482.174 us; speedup vs baseline: 1.2191x; 1.2191x over previous
//
#include <hip/hip_runtime.h>

typedef _Float16 half8 __attribute__((ext_vector_type(8)));
typedef float floatx4 __attribute__((ext_vector_type(4)));

__device__ __forceinline__ float fast_sigmoid(float x) {
    // 1/(1+exp(-x)); exp->inf/0 limits give 0/1 correctly
    return __builtin_amdgcn_rcpf(1.0f + __expf(-x));
}
__device__ __forceinline__ float fast_tanh(float x) {
    // 1 - 2/(exp(2x)+1); inf/0 limits give +/-1 correctly, no clamp needed
    return 1.0f - 2.0f * __builtin_amdgcn_rcpf(__expf(2.0f * x) + 1.0f);
}

// Bidirectional LSTM layer, latency-optimized recurrence.
//   grid = 256 blocks: blockIdx 0..127 fwd (8 batch rows each), 128..255 bwd.
//   block = NW*64 threads, NW = U/16 waves. Wave w owns units [w*16, w*16+16):
//   its 4 MFMA n-tiles are the i,f,g,o columns of those units (weight columns
//   permuted at load time), so gates are computed fully in registers from the
//   accumulators -- no Z round-trip, no second barrier.
//   Per step: x-projection MFMAs (independent of h, issued first) ->
//   one barrier -> ds_read h-frag -> 1-2 dependent h-MFMAs -> gates -> h to
//   double-buffered LDS. x fragments go global->register in A-layout with
//   prefetch distance 2.
template<int F, int U, int XT, bool IN_F32, bool SEQ_OUT>
__global__ __launch_bounds__(64 * (U / 16))
void lstm_layer(const void* __restrict__ in_,
                const float* __restrict__ Wk_f, const float* __restrict__ Wr_f,
                const float* __restrict__ b_f,
                const float* __restrict__ Wk_b, const float* __restrict__ Wr_b,
                const float* __restrict__ b_b,
                _Float16* __restrict__ hseq, float* __restrict__ hlast)
{
    constexpr int T    = 128;
    constexpr int MC   = 8;               // chains per block
    constexpr int N    = 4 * U;
    constexpr int HT   = (U + 31) / 32;   // h k-tiles
    constexpr int KT   = XT + HT;
    constexpr int HROW = HT * 32 + 8;     // f16 elems per h row (16B-aligned, bank-skewed)
    constexpr int NW   = U / 16;          // waves per block
    constexpr int THREADS = NW * 64;

    const int tid  = threadIdx.x;
    const int wave = tid >> 6;
    const int lane = tid & 63;
    const int quad = lane >> 4;
    const int l16  = lane & 15;

    const int dir   = blockIdx.x >> 7;
    const int bbase = (blockIdx.x & 127) * MC;

    const float* Wk = dir ? Wk_b : Wk_f;
    const float* Wr = dir ? Wr_b : Wr_f;
    const float* bs = dir ? b_b  : b_f;

    __shared__ __align__(16) _Float16 H[2][16][HROW];   // double-buffered h

    for (int i = tid; i < 2 * 16 * HROW; i += THREADS)
        (&H[0][0][0])[i] = (_Float16)0;   // h0 = 0; rows 8..15 and pad stay 0 forever

    // Weight fragments, gate-sliced: wave w, gate tile g, col l16 -> n = g*U + w*16 + l16.
    // B-frag layout: lane holds B[k = quad*8+j][n].
    const int ucol = wave * 16 + l16;     // this lane's unit
    half8 bf[4][KT];
    #pragma unroll
    for (int g = 0; g < 4; g++) {
        const int n = g * U + ucol;
        #pragma unroll
        for (int kt = 0; kt < KT; kt++) {
            half8 h;
            #pragma unroll
            for (int j = 0; j < 8; j++) {
                const int k = kt * 32 + quad * 8 + j;
                float v = 0.0f;
                if (kt < XT) { if (k < F) v = Wk[k * N + n]; }
                else { const int ku = k - XT * 32; if (ku < U) v = Wr[ku * N + n]; }
                h[j] = (_Float16)v;
            }
            bf[g][kt] = h;
        }
    }
    float bias[4];
    #pragma unroll
    for (int g = 0; g < 4; g++) bias[g] = bs[g * U + ucol];

    float c_reg[4] = {0.0f, 0.0f, 0.0f, 0.0f};

    const int mrow = l16 & 7;   // clamp dead A-rows 8..15 onto valid addresses
    const long xrow_base = (long)(bbase + mrow) * T;

    auto load_x = [&](int t, half8* xf) {
        const int tc   = t < T ? t : T - 1;          // clamp (tail prefetch)
        const int t_in = dir ? (T - 1 - tc) : tc;
        const long ro  = (xrow_base + t_in) * F;
        #pragma unroll
        for (int kt = 0; kt < XT; kt++) {
            const int kb = kt * 32 + quad * 8;
            half8 h;
            if constexpr (!IN_F32) {
                const _Float16* p = (const _Float16*)in_ + ro;
                if constexpr (F % 32 == 0) {
                    h = *(const half8*)(p + kb);     // 16B aligned
                } else {
                    #pragma unroll
                    for (int j = 0; j < 8; j++) {
                        const int k = kb + j;
                        h[j] = (k < F) ? p[k] : (_Float16)0;
                    }
                }
            } else {
                const float* p = (const float*)in_ + ro;
                #pragma unroll
                for (int j = 0; j < 8; j += 2) {     // 8B-aligned float2 pairs
                    const int k = kb + j;
                    float v0 = 0.0f, v1 = 0.0f;
                    if (k + 2 <= F) { const float2 v = *(const float2*)(p + k); v0 = v.x; v1 = v.y; }
                    else { if (k < F) v0 = p[k]; }
                    h[j] = (_Float16)v0; h[j + 1] = (_Float16)v1;
                }
            }
            xf[kt] = h;
        }
    };

    auto step = [&](int t, half8* xf) {
        // 1) x-projection MFMAs: independent of h(t), off the critical path
        floatx4 acc[4];
        #pragma unroll
        for (int g = 0; g < 4; g++) {
            floatx4 v = {bias[g], bias[g], bias[g], bias[g]};
            acc[g] = v;
        }
        #pragma unroll
        for (int kt = 0; kt < XT; kt++) {
            #pragma unroll
            for (int g = 0; g < 4; g++)
                acc[g] = __builtin_amdgcn_mfma_f32_16x16x32_f16(xf[kt], bf[g][kt], acc[g], 0, 0, 0);
        }
        // 2) prefetch x(t+2) into the same register buffer (distance 2)
        load_x(t + 2, xf);
        // 3) the one barrier: h(t) writes from all waves now visible
        __syncthreads();
        const _Float16* hb = &H[t & 1][l16][0];
        #pragma unroll
        for (int ht = 0; ht < HT; ht++) {
            const half8 ha = *(const half8*)(hb + ht * 32 + quad * 8);
            #pragma unroll
            for (int g = 0; g < 4; g++)
                acc[g] = __builtin_amdgcn_mfma_f32_16x16x32_f16(ha, bf[g][XT + ht], acc[g], 0, 0, 0);
        }
        // 4) gates fully in registers (live rows 0..7 -> quads 0,1)
        if (quad < 2) {
            float hq[4];
            #pragma unroll
            for (int r = 0; r < 4; r++) {
                const float ig = fast_sigmoid(acc[0][r]);
                const float fg = fast_sigmoid(acc[1][r]);
                const float gg = fast_tanh(acc[2][r]);
                const float og = fast_sigmoid(acc[3][r]);
                const float c  = fg * c_reg[r] + ig * gg;
                c_reg[r] = c;
                hq[r] = og * fast_tanh(c);
            }
            #pragma unroll
            for (int r = 0; r < 4; r++)
                H[(t + 1) & 1][quad * 4 + r][ucol] = (_Float16)hq[r];
            if constexpr (SEQ_OUT) {
                const int tp = dir ? (T - 1 - t) : t;   // Keras re-reverses bwd output
                #pragma unroll
                for (int r = 0; r < 4; r++)
                    hseq[((long)(bbase + quad * 4 + r) * T + tp) * (2 * U) + dir * U + ucol] = (_Float16)hq[r];
            } else {
                if (t == T - 1) {
                    #pragma unroll
                    for (int r = 0; r < 4; r++)
                        hlast[(bbase + quad * 4 + r) * (2 * U) + dir * U + ucol] = hq[r];
                }
            }
        }
    };

    half8 xa[XT], xb[XT];
    load_x(0, xa);
    load_x(1, xb);
    __syncthreads();   // H zero-init visible

    for (int tt = 0; tt < T; tt += 2) {
        step(tt,     xa);
        step(tt + 1, xb);
    }
}

__global__ __launch_bounds__(256)
void dense_head(const float* __restrict__ h3,
                const float* __restrict__ w1, const float* __restrict__ b1,
                const float* __restrict__ w2, const float* __restrict__ b2,
                float* __restrict__ out)
{
    const int r = blockIdx.x * 256 + threadIdx.x;
    if (r >= 1024) return;
    float h[32];
    #pragma unroll
    for (int k = 0; k < 32; k++) h[k] = h3[r * 32 + k];
    float d1[8];
    #pragma unroll
    for (int j = 0; j < 8; j++) {
        float a = b1[j];
        #pragma unroll
        for (int k = 0; k < 32; k++) a += h[k] * w1[k * 8 + j];
        d1[j] = fmaxf(a, 0.0f);
    }
    #pragma unroll
    for (int c = 0; c < 3; c++) {
        float s = b2[c];
        #pragma unroll
        for (int j = 0; j < 8; j++) s += d1[j] * w2[j * 3 + c];
        out[r * 3 + c] = 1.0f / (1.0f + __expf(-s));
    }
}

extern "C" void kernel_launch(void* const* d_in, const int* in_sizes, int n_in,
                              void* d_out, int out_size, void* d_ws, size_t ws_size,
                              hipStream_t stream) {
    const float* x     = (const float*)d_in[0];
    const float* w1f_k = (const float*)d_in[1];
    const float* w1f_r = (const float*)d_in[2];
    const float* w1f_b = (const float*)d_in[3];
    const float* w1b_k = (const float*)d_in[4];
    const float* w1b_r = (const float*)d_in[5];
    const float* w1b_b = (const float*)d_in[6];
    const float* w2f_k = (const float*)d_in[7];
    const float* w2f_r = (const float*)d_in[8];
    const float* w2f_b = (const float*)d_in[9];
    const float* w2b_k = (const float*)d_in[10];
    const float* w2b_r = (const float*)d_in[11];
    const float* w2b_b = (const float*)d_in[12];
    const float* w3f_k = (const float*)d_in[13];
    const float* w3f_r = (const float*)d_in[14];
    const float* w3f_b = (const float*)d_in[15];
    const float* w3b_k = (const float*)d_in[16];
    const float* w3b_r = (const float*)d_in[17];
    const float* w3b_b = (const float*)d_in[18];
    const float* d3_w  = (const float*)d_in[19];
    const float* d3_b  = (const float*)d_in[20];
    const float* cls_w = (const float*)d_in[21];
    const float* cls_b = (const float*)d_in[22];

    char* ws = (char*)d_ws;
    _Float16* h1 = (_Float16*)ws;                               // [1024][128][128] f16 = 32MB
    _Float16* h2 = (_Float16*)(ws + (size_t)33554432);          // [1024][128][64]  f16 = 16MB
    float*    h3 = (float*)(ws + (size_t)33554432 + 16777216);  // [1024][32]       f32

    dim3 grid(256);
    // L1: F=78 (3 x-tiles), U=64 -> 4 waves
    lstm_layer<78, 64, 3, true, true><<<grid, dim3(256), 0, stream>>>(
        x, w1f_k, w1f_r, w1f_b, w1b_k, w1b_r, w1b_b, h1, nullptr);
    // L2: F=128 (4 x-tiles), U=32 -> 2 waves
    lstm_layer<128, 32, 4, false, true><<<grid, dim3(128), 0, stream>>>(
        h1, w2f_k, w2f_r, w2f_b, w2b_k, w2b_r, w2b_b, h2, nullptr);
    // L3: F=64 (2 x-tiles), U=16 -> 1 wave, last-state only
    lstm_layer<64, 16, 2, false, false><<<grid, dim3(64), 0, stream>>>(
        h2, w3f_k, w3f_r, w3f_b, w3b_k, w3b_r, w3b_b, nullptr, h3);

    dense_head<<<dim3(4), dim3(256), 0, stream>>>(h3, d3_w, d3_b, cls_w, cls_b, (float*)d_out);
}

// Round 3
// 426.218 us; speedup vs baseline: 1.3792x; 1.1313x over previous
//
#include <hip/hip_runtime.h>

typedef _Float16 half8 __attribute__((ext_vector_type(8)));
typedef float floatx4 __attribute__((ext_vector_type(4)));

__device__ __forceinline__ float fast_sigmoid(float x) {
    // 1/(1+exp(-x)); exp->inf/0 limits give 0/1 correctly
    return __builtin_amdgcn_rcpf(1.0f + __expf(-x));
}
__device__ __forceinline__ float fast_tanh(float x) {
    // 1 - 2/(exp(2x)+1); inf/0 limits give +/-1 correctly
    return 1.0f - 2.0f * __builtin_amdgcn_rcpf(__expf(2.0f * x) + 1.0f);
}

// Workgroup barrier that does NOT drain vmem (unlike __syncthreads, which
// emits s_waitcnt vmcnt(0) before s_barrier and puts prefetch-load + store
// latency on the serial critical path). Only LDS ops are published:
// 0xC07F = vmcnt(63) expcnt(7) lgkmcnt(0) on gfx9 encoding.
template<bool MULTI_WAVE>
__device__ __forceinline__ void lds_publish_barrier() {
    asm volatile("" ::: "memory");
    __builtin_amdgcn_s_waitcnt(0xC07F);
    if constexpr (MULTI_WAVE) __builtin_amdgcn_s_barrier();
    asm volatile("" ::: "memory");
}

// Bidirectional LSTM layer, latency-optimized recurrence.
//   grid = 256 blocks: blockIdx 0..127 fwd (8 batch rows each), 128..255 bwd.
//   block = NW*64 threads, NW = U/16 waves. Wave w owns units [w*16, w*16+16);
//   its 4 MFMA n-tiles are the i,f,g,o columns of those units (weight columns
//   permuted at load), so gates come straight from the accumulators.
//   Per step: x-MFMAs (h-independent, off critical path) -> prefetch x(t+2)
//   -> lgkm-only barrier -> ds_read h -> 1-2 dependent h-MFMAs -> shfl_xor
//   redistribution (all 4 quads share gate work, 2 rows/lane) -> gates in
//   registers -> h to double-buffered LDS.
template<int F, int U, int XT, bool IN_F32, bool SEQ_OUT>
__global__ __launch_bounds__(64 * (U / 16))
void lstm_layer(const void* __restrict__ in_,
                const float* __restrict__ Wk_f, const float* __restrict__ Wr_f,
                const float* __restrict__ b_f,
                const float* __restrict__ Wk_b, const float* __restrict__ Wr_b,
                const float* __restrict__ b_b,
                _Float16* __restrict__ hseq, float* __restrict__ hlast)
{
    constexpr int T    = 128;
    constexpr int MC   = 8;               // chains per block
    constexpr int N    = 4 * U;
    constexpr int HT   = (U + 31) / 32;   // h k-tiles
    constexpr int KT   = XT + HT;
    constexpr int HROW = HT * 32 + 8;     // f16 elems per h row (16B-aligned, bank-skewed)
    constexpr int NW   = U / 16;          // waves per block
    constexpr int THREADS = NW * 64;

    const int tid  = threadIdx.x;
    const int wave = tid >> 6;
    const int lane = tid & 63;
    const int quad = lane >> 4;
    const int l16  = lane & 15;

    const int dir   = blockIdx.x >> 7;
    const int bbase = (blockIdx.x & 127) * MC;

    const float* Wk = dir ? Wk_b : Wk_f;
    const float* Wr = dir ? Wr_b : Wr_f;
    const float* bs = dir ? b_b  : b_f;

    __shared__ __align__(16) _Float16 H[2][16][HROW];   // double-buffered h

    for (int i = tid; i < 2 * 16 * HROW; i += THREADS)
        (&H[0][0][0])[i] = (_Float16)0;   // h0 = 0; rows 8..15 and pad stay 0 forever

    // Weight fragments, gate-sliced: wave w, gate g, col l16 -> n = g*U + w*16 + l16.
    // B-frag layout: lane holds B[k = quad*8+j][n].
    const int ucol = wave * 16 + l16;
    half8 bf[4][KT];
    #pragma unroll
    for (int g = 0; g < 4; g++) {
        const int n = g * U + ucol;
        #pragma unroll
        for (int kt = 0; kt < KT; kt++) {
            half8 h;
            #pragma unroll
            for (int j = 0; j < 8; j++) {
                const int k = kt * 32 + quad * 8 + j;
                float v = 0.0f;
                if (kt < XT) { if (k < F) v = Wk[k * N + n]; }
                else { const int ku = k - XT * 32; if (ku < U) v = Wr[ku * N + n]; }
                h[j] = (_Float16)v;
            }
            bf[g][kt] = h;
        }
    }
    float bias[4];
    #pragma unroll
    for (int g = 0; g < 4; g++) bias[g] = bs[g * U + ucol];

    // Gate-work redistribution: quad q handles 2 rows, rowbase: q0->0, q1->4, q2->2, q3->6
    const int rowbase = (quad & 1) * 4 + (quad >> 1) * 2;
    float c_reg[2] = {0.0f, 0.0f};

    const int mrow = l16 & 7;   // clamp dead A-rows 8..15 onto valid addresses
    const long xrow_base = (long)(bbase + mrow) * T;

    auto load_x = [&](int t, half8* xf) {
        const int tc   = t < T ? t : T - 1;          // clamp (tail prefetch)
        const int t_in = dir ? (T - 1 - tc) : tc;
        const long ro  = (xrow_base + t_in) * F;
        #pragma unroll
        for (int kt = 0; kt < XT; kt++) {
            const int kb = kt * 32 + quad * 8;
            half8 h;
            if constexpr (!IN_F32) {
                const _Float16* p = (const _Float16*)in_ + ro;
                if constexpr (F % 32 == 0) {
                    h = *(const half8*)(p + kb);     // 16B aligned
                } else {
                    #pragma unroll
                    for (int j = 0; j < 8; j++) {
                        const int k = kb + j;
                        h[j] = (k < F) ? p[k] : (_Float16)0;
                    }
                }
            } else {
                const float* p = (const float*)in_ + ro;
                #pragma unroll
                for (int j = 0; j < 8; j += 2) {     // 8B-aligned float2 pairs
                    const int k = kb + j;
                    float v0 = 0.0f, v1 = 0.0f;
                    if (k + 2 <= F) { const float2 v = *(const float2*)(p + k); v0 = v.x; v1 = v.y; }
                    else { if (k < F) v0 = p[k]; }
                    h[j] = (_Float16)v0; h[j + 1] = (_Float16)v1;
                }
            }
            xf[kt] = h;
        }
    };

    auto step = [&](int t, half8* xf) {
        // 1) x-projection MFMAs: independent of h(t)
        floatx4 acc[4];
        #pragma unroll
        for (int g = 0; g < 4; g++) {
            floatx4 v = {bias[g], bias[g], bias[g], bias[g]};
            acc[g] = v;
        }
        #pragma unroll
        for (int kt = 0; kt < XT; kt++) {
            #pragma unroll
            for (int g = 0; g < 4; g++)
                acc[g] = __builtin_amdgcn_mfma_f32_16x16x32_f16(xf[kt], bf[g][kt], acc[g], 0, 0, 0);
        }
        // 2) prefetch x(t+2); stays in flight across the lgkm-only barrier
        load_x(t + 2, xf);
        // 3) publish h(t): LDS-only barrier, no vmem drain
        lds_publish_barrier<(NW > 1)>();
        const _Float16* hb = &H[t & 1][l16][0];
        #pragma unroll
        for (int ht = 0; ht < HT; ht++) {
            const half8 ha = *(const half8*)(hb + ht * 32 + quad * 8);
            #pragma unroll
            for (int g = 0; g < 4; g++)
                acc[g] = __builtin_amdgcn_mfma_f32_16x16x32_f16(ha, bf[g][XT + ht], acc[g], 0, 0, 0);
        }
        // 4) redistribute: quads 2,3 take rows 2,3 / 6,7 from quads 0,1
        float zz[4][2];
        #pragma unroll
        for (int g = 0; g < 4; g++) {
            #pragma unroll
            for (int s = 0; s < 2; s++) {
                const float hi = __shfl_xor(acc[g][2 + s], 32, 64);
                zz[g][s] = (quad < 2) ? acc[g][s] : hi;
            }
        }
        // 5) gates: 2 rows per lane, all lanes active
        float hq[2];
        #pragma unroll
        for (int s = 0; s < 2; s++) {
            const float ig = fast_sigmoid(zz[0][s]);
            const float fg = fast_sigmoid(zz[1][s]);
            const float gg = fast_tanh(zz[2][s]);
            const float og = fast_sigmoid(zz[3][s]);
            const float c  = fg * c_reg[s] + ig * gg;
            c_reg[s] = c;
            hq[s] = og * fast_tanh(c);
        }
        #pragma unroll
        for (int s = 0; s < 2; s++)
            H[(t + 1) & 1][rowbase + s][ucol] = (_Float16)hq[s];
        if constexpr (SEQ_OUT) {
            const int tp = dir ? (T - 1 - t) : t;   // Keras re-reverses bwd output
            #pragma unroll
            for (int s = 0; s < 2; s++)
                hseq[((long)(bbase + rowbase + s) * T + tp) * (2 * U) + dir * U + ucol] = (_Float16)hq[s];
        } else {
            if (t == T - 1) {
                #pragma unroll
                for (int s = 0; s < 2; s++)
                    hlast[(bbase + rowbase + s) * (2 * U) + dir * U + ucol] = hq[s];
            }
        }
    };

    half8 xa[XT], xb[XT];
    load_x(0, xa);
    load_x(1, xb);
    __syncthreads();   // once: H zero-init visible (vmem drain harmless here)

    for (int tt = 0; tt < T; tt += 2) {
        step(tt,     xa);
        step(tt + 1, xb);
    }
}

__global__ __launch_bounds__(256)
void dense_head(const float* __restrict__ h3,
                const float* __restrict__ w1, const float* __restrict__ b1,
                const float* __restrict__ w2, const float* __restrict__ b2,
                float* __restrict__ out)
{
    const int r = blockIdx.x * 256 + threadIdx.x;
    if (r >= 1024) return;
    float h[32];
    #pragma unroll
    for (int k = 0; k < 32; k++) h[k] = h3[r * 32 + k];
    float d1[8];
    #pragma unroll
    for (int j = 0; j < 8; j++) {
        float a = b1[j];
        #pragma unroll
        for (int k = 0; k < 32; k++) a += h[k] * w1[k * 8 + j];
        d1[j] = fmaxf(a, 0.0f);
    }
    #pragma unroll
    for (int c = 0; c < 3; c++) {
        float s = b2[c];
        #pragma unroll
        for (int j = 0; j < 8; j++) s += d1[j] * w2[j * 3 + c];
        out[r * 3 + c] = 1.0f / (1.0f + __expf(-s));
    }
}

extern "C" void kernel_launch(void* const* d_in, const int* in_sizes, int n_in,
                              void* d_out, int out_size, void* d_ws, size_t ws_size,
                              hipStream_t stream) {
    const float* x     = (const float*)d_in[0];
    const float* w1f_k = (const float*)d_in[1];
    const float* w1f_r = (const float*)d_in[2];
    const float* w1f_b = (const float*)d_in[3];
    const float* w1b_k = (const float*)d_in[4];
    const float* w1b_r = (const float*)d_in[5];
    const float* w1b_b = (const float*)d_in[6];
    const float* w2f_k = (const float*)d_in[7];
    const float* w2f_r = (const float*)d_in[8];
    const float* w2f_b = (const float*)d_in[9];
    const float* w2b_k = (const float*)d_in[10];
    const float* w2b_r = (const float*)d_in[11];
    const float* w2b_b = (const float*)d_in[12];
    const float* w3f_k = (const float*)d_in[13];
    const float* w3f_r = (const float*)d_in[14];
    const float* w3f_b = (const float*)d_in[15];
    const float* w3b_k = (const float*)d_in[16];
    const float* w3b_r = (const float*)d_in[17];
    const float* w3b_b = (const float*)d_in[18];
    const float* d3_w  = (const float*)d_in[19];
    const float* d3_b  = (const float*)d_in[20];
    const float* cls_w = (const float*)d_in[21];
    const float* cls_b = (const float*)d_in[22];

    char* ws = (char*)d_ws;
    _Float16* h1 = (_Float16*)ws;                               // [1024][128][128] f16 = 32MB
    _Float16* h2 = (_Float16*)(ws + (size_t)33554432);          // [1024][128][64]  f16 = 16MB
    float*    h3 = (float*)(ws + (size_t)33554432 + 16777216);  // [1024][32]       f32

    dim3 grid(256);
    // L1: F=78 (3 x-tiles), U=64 -> 4 waves
    lstm_layer<78, 64, 3, true, true><<<grid, dim3(256), 0, stream>>>(
        x, w1f_k, w1f_r, w1f_b, w1b_k, w1b_r, w1b_b, h1, nullptr);
    // L2: F=128 (4 x-tiles), U=32 -> 2 waves
    lstm_layer<128, 32, 4, false, true><<<grid, dim3(128), 0, stream>>>(
        h1, w2f_k, w2f_r, w2f_b, w2b_k, w2b_r, w2b_b, h2, nullptr);
    // L3: F=64 (2 x-tiles), U=16 -> 1 wave, last-state only
    lstm_layer<64, 16, 2, false, false><<<grid, dim3(64), 0, stream>>>(
        h2, w3f_k, w3f_r, w3f_b, w3b_k, w3b_r, w3b_b, nullptr, h3);

    dense_head<<<dim3(4), dim3(256), 0, stream>>>(h3, d3_w, d3_b, cls_w, cls_b, (float*)d_out);
}